// Round 9
// baseline (363.750 us; speedup 1.0000x reference)
//
#include <hip/hip_runtime.h>

// ---------------------------------------------------------------------------
// Fused MHA forward on MI355X (gfx950), bf16 MFMA path, round 14 (resubmit;
// round-8 bench was an infra container failure — same signature as rounds
// 0/4, and the round-4 identical-resubmit then ran clean).
// B=8, N=1024, C=1024, H=16, D=64.  M = B*N = 8192.
// ws (64 MB): [0,16M) xb then ob; [16,32M) qb then woutb; [32,48M) kb;
//             [48,64M) vbT.   d_out: [0,6M) winb (dead before out_gemm).
// NEW vs round 13 (attn only; GEMMs unchanged):
//  * attn is BARRIER-FREE: K/V LDS staging deleted; each wave loads K and
//    V MFMA fragments directly global->VGPR (L2-resident per XCD swizzle;
//    per-CU working set ~4MB fits L2). P scratch in per-wave-PRIVATE LDS
//    (in-order DS pipe, no barrier). Zero __syncthreads -> waves free-run
//    and de-phase: MFMA of one wave overlaps softmax VALU of another and
//    load-wait of a third. R9's direct-load failure was vmcnt-queue
//    poisoning vs gl16 prefetch + forced drains; with no gl16 and no
//    barrier the compiler's counted waits are monotone (K->mask->V).
//    LDS 16KB (lsp only); VGPR ~160 -> 3 waves/SIMD.
// ---------------------------------------------------------------------------

typedef __bf16 bf16x8 __attribute__((ext_vector_type(8)));
typedef float f32x4 __attribute__((ext_vector_type(4)));
typedef unsigned short us4v __attribute__((ext_vector_type(4)));

#define MFMA16 __builtin_amdgcn_mfma_f32_16x16x32_bf16

__device__ __forceinline__ unsigned short f2bf(float f) {
    return __builtin_bit_cast(unsigned short, (__bf16)f);   // native cvt, RNE
}

__device__ __forceinline__ us4v cvt4(float4 v) {
    us4v r;
    r.x = f2bf(v.x); r.y = f2bf(v.y); r.z = f2bf(v.z); r.w = f2bf(v.w);
    return r;
}

// async global->LDS, 16 B per lane; LDS dest = wave-uniform base + lane*16
__device__ __forceinline__ void gl16(const unsigned short* g, unsigned short* l) {
    __builtin_amdgcn_global_load_lds(
        (const __attribute__((address_space(1))) unsigned*)g,
        (__attribute__((address_space(3))) unsigned*)l, 16, 0, 0);
}

// ---------------------------------------------------------------------------
// Kernel 0: fp32 -> bf16 convert (one float4 per thread)
// ---------------------------------------------------------------------------
__global__ __launch_bounds__(256)
void cvt_bf16(const float* __restrict__ src, unsigned short* __restrict__ dst,
              int n4) {
    const int i = blockIdx.x * 256 + threadIdx.x;
    if (i < n4) {
        float4 v = ((const float4*)src)[i];
        ((us4v*)dst)[i] = cvt4(v);
    }
}

// ---------------------------------------------------------------------------
// Kernel 1: qkv = xb @ winb^T + b_in -> q (x0.125), k in (B,H,N,D) bf16,
//           V written directly transposed as vbT (B,H,D,N) bf16.
// Triple-buffered counted-vmcnt pipeline (prefetch distance 2).
// ---------------------------------------------------------------------------
__global__ __launch_bounds__(256, 3)
void qkv_gemm(const unsigned short* __restrict__ xb,   // (8192,1024) bf16
              const unsigned short* __restrict__ wb,   // (3072,1024) bf16
              const float* __restrict__ bias,
              unsigned short* __restrict__ qb, unsigned short* __restrict__ kb,
              unsigned short* __restrict__ vbT)
{
    __shared__ unsigned short lsa[3][128 * 32];
    __shared__ unsigned short lsb[3][128 * 32];
    const int tid  = threadIdx.x;
    const int wave = tid >> 6, lane = tid & 63;
    const int quad = lane >> 4, l15 = lane & 15;
    const int rch = (quad ^ ((l15 >> 1) & 3)) * 8;   // swizzled read chunk
    const int m0 = blockIdx.x * 128, n0 = blockIdx.y * 128;
    const int wm = (wave & 1) * 64, wn = (wave >> 1) * 64;

    const int srow = wave * 32 + (lane >> 2);
    const int scol = ((lane & 3) ^ ((lane >> 3) & 3)) * 8;   // swizzled stage
    const unsigned short* ga = xb + (size_t)(m0 + srow) * 1024 + scol;
    const unsigned short* gb = wb + (size_t)(n0 + srow) * 1024 + scol;
    const int so0 = (wave * 32) * 32;          // stage offsets within a buffer
    const int so1 = (wave * 32 + 16) * 32;

    f32x4 acc[4][4];
#pragma unroll
    for (int i = 0; i < 4; ++i)
#pragma unroll
        for (int j = 0; j < 4; ++j) acc[i][j] = (f32x4){0.f, 0.f, 0.f, 0.f};

    // prologue: stage kt=0 -> buf0, kt=1 -> buf1 (no wait; loop handles it)
    gl16(ga, &lsa[0][so0]);
    gl16(ga + 16 * 1024, &lsa[0][so1]);
    gl16(gb, &lsb[0][so0]);
    gl16(gb + 16 * 1024, &lsb[0][so1]);
    gl16(ga + 32, &lsa[1][so0]);
    gl16(ga + 16 * 1024 + 32, &lsa[1][so1]);
    gl16(gb + 32, &lsb[1][so0]);
    gl16(gb + 16 * 1024 + 32, &lsb[1][so1]);

    for (int kt = 0; kt < 32; ++kt) {
        const int cb = kt % 3;
        if (kt < 30) {                         // stage kt+2 (distance 2)
            const int k0 = (kt + 2) * 32;
            const int sb = (kt + 2) % 3;
            gl16(ga + k0, &lsa[sb][so0]);
            gl16(ga + 16 * 1024 + k0, &lsa[sb][so1]);
            gl16(gb + k0, &lsb[sb][so0]);
            gl16(gb + 16 * 1024 + k0, &lsb[sb][so1]);
            asm volatile("s_waitcnt vmcnt(8)" ::: "memory");  // tile kt landed
        } else if (kt == 30) {
            asm volatile("s_waitcnt vmcnt(4)" ::: "memory");
        } else {
            asm volatile("s_waitcnt vmcnt(0)" ::: "memory");
        }
        __builtin_amdgcn_s_barrier();

        const unsigned short* pa = lsa[cb];
        const unsigned short* pb = lsb[cb];
        bf16x8 af[4], bfr[4];
#pragma unroll
        for (int i = 0; i < 4; ++i)
            af[i] = *(const bf16x8*)&pa[(wm + i * 16 + l15) * 32 + rch];
#pragma unroll
        for (int j = 0; j < 4; ++j)
            bfr[j] = *(const bf16x8*)&pb[(wn + j * 16 + l15) * 32 + rch];
#pragma unroll
        for (int i = 0; i < 4; ++i)
#pragma unroll
            for (int j = 0; j < 4; ++j)
                acc[i][j] = MFMA16(af[i], bfr[j], acc[i][j], 0, 0, 0);

        asm volatile("s_waitcnt lgkmcnt(0)" ::: "memory");  // reads done
        __builtin_amdgcn_sched_barrier(0);
        __builtin_amdgcn_s_barrier();          // protect buf reuse (kt+3)
    }

    const int which = n0 >> 10;
    if (which == 2) {
        // V: write transposed (bh, d, seq); (i,r) axis is seq -> pack 4 bf16.
#pragma unroll
        for (int j = 0; j < 4; ++j) {
            const int n = n0 + wn + j * 16 + l15;
            const int c = n & 1023;
            const int h = c >> 6, d = c & 63;
            const float bv = bias[n];
#pragma unroll
            for (int i = 0; i < 4; ++i) {
                const int m = m0 + wm + i * 16 + quad * 4;   // r=0 row
                const int b = m >> 10, s = m & 1023;
                us4v pk;
#pragma unroll
                for (int r = 0; r < 4; ++r) pk[r] = f2bf(acc[i][j][r] + bv);
                *(us4v*)&vbT[(size_t)((b * 16 + h) * 64 + d) * 1024 + s] = pk;
            }
        }
    } else {
        unsigned short* __restrict__ dst = (which == 0) ? qb : kb;
        const float sc = (which == 0) ? 0.125f : 1.0f;   // q / sqrt(64)
#pragma unroll
        for (int j = 0; j < 4; ++j) {
            const int n = n0 + wn + j * 16 + l15;
            const int c = n & 1023;
            const int h = c >> 6, d = c & 63;
            const float bv = bias[n];
#pragma unroll
            for (int i = 0; i < 4; ++i)
#pragma unroll
                for (int r = 0; r < 4; ++r) {
                    const int m = m0 + wm + i * 16 + quad * 4 + r;
                    const int b = m >> 10, s = m & 1023;
                    const float v = (acc[i][j][r] + bv) * sc;
                    dst[(size_t)((b * 16 + h) * 1024 + s) * 64 + d] = f2bf(v);
                }
        }
    }
}

// ---------------------------------------------------------------------------
// Kernel 2: flash attention, swapped-QK^T, QBLK=128, BARRIER-FREE.
//   No K/V LDS staging: per-wave direct global->VGPR fragment loads
//   (L2-resident; XCD swizzle keeps per-L2 working set ~4MB). P in
//   per-wave-private swizzled LDS. Zero __syncthreads -> waves de-phase
//   and fill each other's pipe bubbles (MFMA || VALU || load-wait).
//   S^T = MFMA(K,Q): lane (quad,l15) holds S[q=l15][key=quad*4+r].
// LDS 16KB; VGPR-bound ~3 waves/SIMD. Grid 1024, XCD-swizzled.
// ---------------------------------------------------------------------------
__global__ __launch_bounds__(256, 3)
void attn_kernel(const unsigned short* __restrict__ qb,
                 const unsigned short* __restrict__ kb,
                 const unsigned short* __restrict__ vbT,  // (bh, d, n)
                 const float* __restrict__ mask,
                 unsigned short* __restrict__ ob)   // (B, N, C) bf16
{
    __shared__ unsigned short lsp[4][2][16 * 64];     // [wave][grp], swizzled
    const int tid  = threadIdx.x;
    const int wave = tid >> 6, lane = tid & 63;
    const int quad = lane >> 4, l15 = lane & 15;
    const int swz = (l15 & 7) << 3;                  // P granule swizzle
    const int p  = blockIdx.x;
    const int lg = (p & 7) * 128 + (p >> 3);         // XCD swizzle (bijective)
    const int bh = lg >> 3;                          // b*16+h
    const int q0 = (lg & 7) * 128;
    const int b = bh >> 4, h = bh & 15;

    // Direct per-lane fragment bases (A-operand: m=l15, k=quad*8+j):
    //  K frag (nt,half):  K[key = kt*64+nt*16+l15][half*32 + quad*8 ..+8)
    //  V frag (nt,half):  V^T[d = nt*16+l15][kt*64 + half*32 + quad*8 ..+8)
    const unsigned short* gk =
        kb + (size_t)bh * 65536 + (size_t)l15 * 64 + quad * 8;
    const unsigned short* gv =
        vbT + (size_t)bh * 65536 + (size_t)l15 * 1024 + quad * 8;

    // Q fragments, 2 groups (B-operand: n = l15 = q, k = quad*8+j = d)
    bf16x8 bq[2][2];
#pragma unroll
    for (int g = 0; g < 2; ++g) {
        const unsigned short* qrow =
            qb + (size_t)(bh * 1024 + q0 + wave * 32 + g * 16 + l15) * 64;
        bq[g][0] = *(const bf16x8*)(qrow + quad * 8);
        bq[g][1] = *(const bf16x8*)(qrow + 32 + quad * 8);
    }

    float lsum[2] = {0.f, 0.f};
    f32x4 oacc[2][4];              // [grp][nt]: O[q=l15][d=nt*16+quad*4+r]
#pragma unroll
    for (int g = 0; g < 2; ++g)
#pragma unroll
        for (int nt = 0; nt < 4; ++nt) oacc[g][nt] = (f32x4){0.f, 0.f, 0.f, 0.f};

    const float* __restrict__ mrow0 =
        mask + (size_t)(q0 + wave * 32 + l15) * 1024;
    const float* __restrict__ mrow1 = mrow0 + 16 * 1024;
    unsigned short* lp0 = lsp[wave][0];
    unsigned short* lp1 = lsp[wave][1];

    for (int kt = 0; kt < 16; ++kt) {
        // K fragments for this tile (first use: QK^T)
        bf16x8 kf[4][2];
#pragma unroll
        for (int nt = 0; nt < 4; ++nt) {
            const unsigned short* kr = gk + (size_t)(kt * 64 + nt * 16) * 64;
            kf[nt][0] = *(const bf16x8*)(kr);
            kf[nt][1] = *(const bf16x8*)(kr + 32);
        }
        // mask for this tile (first use: softmax)
        float4 mv[2][4];
#pragma unroll
        for (int nt = 0; nt < 4; ++nt) {
            mv[0][nt] = *(const float4*)&mrow0[kt * 64 + nt * 16 + quad * 4];
            mv[1][nt] = *(const float4*)&mrow1[kt * 64 + nt * 16 + quad * 4];
        }
        // V fragments for this tile (first use: PV — latency hides under
        // QK^T + softmax via the compiler's counted vmcnt)
        bf16x8 vf[4][2];
#pragma unroll
        for (int nt = 0; nt < 4; ++nt) {
            const unsigned short* vr = gv + (size_t)nt * 16 * 1024 + kt * 64;
            vf[nt][0] = *(const bf16x8*)(vr);
            vf[nt][1] = *(const bf16x8*)(vr + 32);
        }

        // S^T = K Q^T  (C-layout: row=key=quad*4+r, col=q=l15), both groups
        f32x4 s[2][4];
        __builtin_amdgcn_s_setprio(1);
#pragma unroll
        for (int nt = 0; nt < 4; ++nt) {
            s[0][nt] = MFMA16(kf[nt][0], bq[0][0],
                              (f32x4){0.f, 0.f, 0.f, 0.f}, 0, 0, 0);
            s[0][nt] = MFMA16(kf[nt][1], bq[0][1], s[0][nt], 0, 0, 0);
            s[1][nt] = MFMA16(kf[nt][0], bq[1][0],
                              (f32x4){0.f, 0.f, 0.f, 0.f}, 0, 0, 0);
            s[1][nt] = MFMA16(kf[nt][1], bq[1][1], s[1][nt], 0, 0, 0);
        }
        __builtin_amdgcn_s_setprio(0);

        // p = exp(s + mask) -> per-group swizzled private lsp
#pragma unroll
        for (int nt = 0; nt < 4; ++nt) {
            us4v pk0, pk1;
#pragma unroll
            for (int r = 0; r < 4; ++r) {
                const float pe0 =
                    __expf(s[0][nt][r] + ((const float*)&mv[0][nt])[r]);
                const float pe1 =
                    __expf(s[1][nt][r] + ((const float*)&mv[1][nt])[r]);
                lsum[0] += pe0;
                lsum[1] += pe1;
                pk0[r] = f2bf(pe0);
                pk1[r] = f2bf(pe1);
            }
            const int off = (nt * 16 + quad * 4) ^ swz;
            *(us4v*)&lp0[(l15 << 6) + off] = pk0;
            *(us4v*)&lp1[(l15 << 6) + off] = pk1;
        }
        bf16x8 pb0[2], pb1[2];
        pb0[0] = *(const bf16x8*)&lp0[(l15 << 6) + ((quad * 8) ^ swz)];
        pb0[1] = *(const bf16x8*)&lp0[(l15 << 6) + ((32 + quad * 8) ^ swz)];
        pb1[0] = *(const bf16x8*)&lp1[(l15 << 6) + ((quad * 8) ^ swz)];
        pb1[1] = *(const bf16x8*)&lp1[(l15 << 6) + ((32 + quad * 8) ^ swz)];

        // O += P V via O = (V^T as A) x (P^T as B): C row=d, col=q
        __builtin_amdgcn_s_setprio(1);
#pragma unroll
        for (int nt = 0; nt < 4; ++nt) {
            oacc[0][nt] = MFMA16(vf[nt][0], pb0[0], oacc[0][nt], 0, 0, 0);
            oacc[0][nt] = MFMA16(vf[nt][1], pb0[1], oacc[0][nt], 0, 0, 0);
            oacc[1][nt] = MFMA16(vf[nt][0], pb1[0], oacc[1][nt], 0, 0, 0);
            oacc[1][nt] = MFMA16(vf[nt][1], pb1[1], oacc[1][nt], 0, 0, 0);
        }
        __builtin_amdgcn_s_setprio(0);
    }

    // row-sum: partial sums per-quad; reduce across lane bits 4,5
#pragma unroll
    for (int g = 0; g < 2; ++g) {
        lsum[g] += __shfl_xor(lsum[g], 16, 64);
        lsum[g] += __shfl_xor(lsum[g], 32, 64);
    }
#pragma unroll
    for (int g = 0; g < 2; ++g) {
        const float inv = 1.0f / lsum[g];
        unsigned short* orow =
            ob + (size_t)(b * 1024 + q0 + wave * 32 + g * 16 + l15) * 1024
               + h * 64;
#pragma unroll
        for (int nt = 0; nt < 4; ++nt) {
            us4v o;
#pragma unroll
            for (int r = 0; r < 4; ++r) o[r] = f2bf(oacc[g][nt][r] * inv);
            *(us4v*)&orow[nt * 16 + quad * 4] = o;
        }
    }
}

// ---------------------------------------------------------------------------
// Kernel 3: out = ob(bf16) @ woutb^T + out_b, fp32 to d_out.
// Triple-buffered counted-vmcnt pipeline (prefetch distance 2).
// ---------------------------------------------------------------------------
__global__ __launch_bounds__(256, 3)
void out_gemm(const unsigned short* __restrict__ a,   // (8192,1024) bf16
              const unsigned short* __restrict__ wb,  // (1024,1024) bf16
              const float* __restrict__ bias, float* __restrict__ out)
{
    __shared__ unsigned short lsa[3][128 * 32];
    __shared__ unsigned short lsb[3][128 * 32];
    const int tid  = threadIdx.x;
    const int wave = tid >> 6, lane = tid & 63;
    const int quad = lane >> 4, l15 = lane & 15;
    const int rch = (quad ^ ((l15 >> 1) & 3)) * 8;
    const int m0 = blockIdx.x * 128, n0 = blockIdx.y * 128;
    const int wm = (wave & 1) * 64, wn = (wave >> 1) * 64;

    const int srow = wave * 32 + (lane >> 2);
    const int scol = ((lane & 3) ^ ((lane >> 3) & 3)) * 8;
    const unsigned short* ga = a + (size_t)(m0 + srow) * 1024 + scol;
    const unsigned short* gb = wb + (size_t)(n0 + srow) * 1024 + scol;
    const int so0 = (wave * 32) * 32;
    const int so1 = (wave * 32 + 16) * 32;

    f32x4 acc[4][4];
#pragma unroll
    for (int i = 0; i < 4; ++i)
#pragma unroll
        for (int j = 0; j < 4; ++j) acc[i][j] = (f32x4){0.f, 0.f, 0.f, 0.f};

    gl16(ga, &lsa[0][so0]);
    gl16(ga + 16 * 1024, &lsa[0][so1]);
    gl16(gb, &lsb[0][so0]);
    gl16(gb + 16 * 1024, &lsb[0][so1]);
    gl16(ga + 32, &lsa[1][so0]);
    gl16(ga + 16 * 1024 + 32, &lsa[1][so1]);
    gl16(gb + 32, &lsb[1][so0]);
    gl16(gb + 16 * 1024 + 32, &lsb[1][so1]);

    for (int kt = 0; kt < 32; ++kt) {
        const int cb = kt % 3;
        if (kt < 30) {
            const int k0 = (kt + 2) * 32;
            const int sb = (kt + 2) % 3;
            gl16(ga + k0, &lsa[sb][so0]);
            gl16(ga + 16 * 1024 + k0, &lsa[sb][so1]);
            gl16(gb + k0, &lsb[sb][so0]);
            gl16(gb + 16 * 1024 + k0, &lsb[sb][so1]);
            asm volatile("s_waitcnt vmcnt(8)" ::: "memory");
        } else if (kt == 30) {
            asm volatile("s_waitcnt vmcnt(4)" ::: "memory");
        } else {
            asm volatile("s_waitcnt vmcnt(0)" ::: "memory");
        }
        __builtin_amdgcn_s_barrier();

        const unsigned short* pa = lsa[cb];
        const unsigned short* pb = lsb[cb];
        bf16x8 af[4], bfr[4];
#pragma unroll
        for (int i = 0; i < 4; ++i)
            af[i] = *(const bf16x8*)&pa[(wm + i * 16 + l15) * 32 + rch];
#pragma unroll
        for (int j = 0; j < 4; ++j)
            bfr[j] = *(const bf16x8*)&pb[(wn + j * 16 + l15) * 32 + rch];
#pragma unroll
        for (int i = 0; i < 4; ++i)
#pragma unroll
            for (int j = 0; j < 4; ++j)
                acc[i][j] = MFMA16(af[i], bfr[j], acc[i][j], 0, 0, 0);

        asm volatile("s_waitcnt lgkmcnt(0)" ::: "memory");
        __builtin_amdgcn_sched_barrier(0);
        __builtin_amdgcn_s_barrier();
    }

#pragma unroll
    for (int j = 0; j < 4; ++j) {
        const int n = n0 + wn + j * 16 + l15;
        const float bv = bias[n];
#pragma unroll
        for (int i = 0; i < 4; ++i)
#pragma unroll
            for (int r = 0; r < 4; ++r) {
                const int m = m0 + wm + i * 16 + quad * 4 + r;
                out[(size_t)m * 1024 + n] = acc[i][j][r] + bv;
            }
    }
}

// ---------------------------------------------------------------------------
extern "C" void kernel_launch(void* const* d_in, const int* in_sizes, int n_in,
                              void* d_out, int out_size, void* d_ws, size_t ws_size,
                              hipStream_t stream) {
    const float* x    = (const float*)d_in[0];   // (8, 1024, 1024)
    const float* mask = (const float*)d_in[1];   // (1024, 1024)
    const float* win  = (const float*)d_in[2];   // (3072, 1024)
    const float* bin  = (const float*)d_in[3];   // (3072)
    const float* wout = (const float*)d_in[4];   // (1024, 1024)
    const float* bout = (const float*)d_in[5];   // (1024)
    float* out = (float*)d_out;                  // (8, 1024, 1024)

    char* ws = (char*)d_ws;
    unsigned short* xb = (unsigned short*)(ws);
    unsigned short* ob = (unsigned short*)(ws);                       // overlays xb
    unsigned short* qb = (unsigned short*)(ws + (size_t)(16 << 20));
    unsigned short* kb = (unsigned short*)(ws + (size_t)(32 << 20));
    unsigned short* vbT = (unsigned short*)(ws + (size_t)(48 << 20));
    unsigned short* winb  = (unsigned short*)d_out;                   // [0, 6M)
    unsigned short* woutb = qb;   // overlays qb AFTER attn (qb dead) — no race

    cvt_bf16<<<dim3(8192), 256, 0, stream>>>(x, xb, 8 * 1024 * 1024 / 4);
    cvt_bf16<<<dim3(3072), 256, 0, stream>>>(win, winb, 3 * 1024 * 1024 / 4);
    qkv_gemm<<<dim3(64, 24), 256, 0, stream>>>(xb, winb, bin, qb, kb, vbT);
    attn_kernel<<<dim3(1024), 256, 0, stream>>>(qb, kb, vbT, mask, ob);
    cvt_bf16<<<dim3(1024), 256, 0, stream>>>(wout, woutb, 1024 * 1024 / 4);
    out_gemm<<<dim3(64, 8), 256, 0, stream>>>(ob, woutb, bout, out);
}

// Round 10
// 293.742 us; speedup vs baseline: 1.2383x; 1.2383x over previous
//
#include <hip/hip_runtime.h>

// ---------------------------------------------------------------------------
// Fused MHA forward on MI355X (gfx950), bf16 MFMA path, round 15.
// B=8, N=1024, C=1024, H=16, D=64.  M = B*N = 8192.
// ws (64 MB): [0,16M) xb then ob; [16,32M) qb then woutb; [32,48M) kb;
//             [48,64M) vbT.
// d_out: [0,6M) winb; [6M,10M) mask*log2e — both dead before out_gemm writes.
// NEW vs round 14 (attn rebuilt; GEMMs = R13):
//  * attn: KEY-SPLIT barrier-free waves. Block=64q, wave w owns keys
//    [256w,256w+256) for ALL 64 q (4 groups of 16). Per-wave PRIVATE K/V
//    LDS dbuf staged via gl16 (coalesced — R14's scattered direct loads
//    were the regression); zero barriers in the loop; vmcnt(16) counted
//    waits (next tile + next masks stay in flight). Mask enters as the
//    MFMA C-operand (exact C layout) — no VALU add; mask pre-scaled by
//    log2e, q by 0.125*log2e -> softmax is bare exp2f. Split-key combine
//    via LDS arena overlay + ONE __syncthreads at the end.
//    LDS 80KB -> 2 blocks/CU; ~230 VGPR -> 2 waves/SIMD, waves de-phase.
// ---------------------------------------------------------------------------

typedef __bf16 bf16x8 __attribute__((ext_vector_type(8)));
typedef float f32x4 __attribute__((ext_vector_type(4)));
typedef unsigned short us4v __attribute__((ext_vector_type(4)));

#define MFMA16 __builtin_amdgcn_mfma_f32_16x16x32_bf16

__device__ __forceinline__ unsigned short f2bf(float f) {
    return __builtin_bit_cast(unsigned short, (__bf16)f);   // native cvt, RNE
}

__device__ __forceinline__ us4v cvt4(float4 v) {
    us4v r;
    r.x = f2bf(v.x); r.y = f2bf(v.y); r.z = f2bf(v.z); r.w = f2bf(v.w);
    return r;
}

// async global->LDS, 16 B per lane; LDS dest = wave-uniform base + lane*16
__device__ __forceinline__ void gl16(const unsigned short* g, unsigned short* l) {
    __builtin_amdgcn_global_load_lds(
        (const __attribute__((address_space(1))) unsigned*)g,
        (__attribute__((address_space(3))) unsigned*)l, 16, 0, 0);
}

// ---------------------------------------------------------------------------
// Kernel 0: fp32 -> bf16 convert (one float4 per thread)
// ---------------------------------------------------------------------------
__global__ __launch_bounds__(256)
void cvt_bf16(const float* __restrict__ src, unsigned short* __restrict__ dst,
              int n4) {
    const int i = blockIdx.x * 256 + threadIdx.x;
    if (i < n4) {
        float4 v = ((const float4*)src)[i];
        ((us4v*)dst)[i] = cvt4(v);
    }
}

// Kernel 0b: scale f32 by log2(e) (for exp2-domain softmax)
__global__ __launch_bounds__(256)
void scale_f32(const float* __restrict__ src, float* __restrict__ dst, int n4) {
    const int i = blockIdx.x * 256 + threadIdx.x;
    if (i < n4) {
        float4 v = ((const float4*)src)[i];
        const float s = 1.4426950408889634f;
        v.x *= s; v.y *= s; v.z *= s; v.w *= s;
        ((float4*)dst)[i] = v;
    }
}

// ---------------------------------------------------------------------------
// Kernel 1: qkv = xb @ winb^T + b_in -> q (x0.125*log2e), k in (B,H,N,D),
//           V written directly transposed as vbT (B,H,D,N) bf16.
// Triple-buffered counted-vmcnt pipeline (R13, unchanged except q scale).
// ---------------------------------------------------------------------------
__global__ __launch_bounds__(256, 3)
void qkv_gemm(const unsigned short* __restrict__ xb,   // (8192,1024) bf16
              const unsigned short* __restrict__ wb,   // (3072,1024) bf16
              const float* __restrict__ bias,
              unsigned short* __restrict__ qb, unsigned short* __restrict__ kb,
              unsigned short* __restrict__ vbT)
{
    __shared__ unsigned short lsa[3][128 * 32];
    __shared__ unsigned short lsb[3][128 * 32];
    const int tid  = threadIdx.x;
    const int wave = tid >> 6, lane = tid & 63;
    const int quad = lane >> 4, l15 = lane & 15;
    const int rch = (quad ^ ((l15 >> 1) & 3)) * 8;   // swizzled read chunk
    const int m0 = blockIdx.x * 128, n0 = blockIdx.y * 128;
    const int wm = (wave & 1) * 64, wn = (wave >> 1) * 64;

    const int srow = wave * 32 + (lane >> 2);
    const int scol = ((lane & 3) ^ ((lane >> 3) & 3)) * 8;   // swizzled stage
    const unsigned short* ga = xb + (size_t)(m0 + srow) * 1024 + scol;
    const unsigned short* gb = wb + (size_t)(n0 + srow) * 1024 + scol;
    const int so0 = (wave * 32) * 32;          // stage offsets within a buffer
    const int so1 = (wave * 32 + 16) * 32;

    f32x4 acc[4][4];
#pragma unroll
    for (int i = 0; i < 4; ++i)
#pragma unroll
        for (int j = 0; j < 4; ++j) acc[i][j] = (f32x4){0.f, 0.f, 0.f, 0.f};

    gl16(ga, &lsa[0][so0]);
    gl16(ga + 16 * 1024, &lsa[0][so1]);
    gl16(gb, &lsb[0][so0]);
    gl16(gb + 16 * 1024, &lsb[0][so1]);
    gl16(ga + 32, &lsa[1][so0]);
    gl16(ga + 16 * 1024 + 32, &lsa[1][so1]);
    gl16(gb + 32, &lsb[1][so0]);
    gl16(gb + 16 * 1024 + 32, &lsb[1][so1]);

    for (int kt = 0; kt < 32; ++kt) {
        const int cb = kt % 3;
        if (kt < 30) {                         // stage kt+2 (distance 2)
            const int k0 = (kt + 2) * 32;
            const int sb = (kt + 2) % 3;
            gl16(ga + k0, &lsa[sb][so0]);
            gl16(ga + 16 * 1024 + k0, &lsa[sb][so1]);
            gl16(gb + k0, &lsb[sb][so0]);
            gl16(gb + 16 * 1024 + k0, &lsb[sb][so1]);
            asm volatile("s_waitcnt vmcnt(8)" ::: "memory");
        } else if (kt == 30) {
            asm volatile("s_waitcnt vmcnt(4)" ::: "memory");
        } else {
            asm volatile("s_waitcnt vmcnt(0)" ::: "memory");
        }
        __builtin_amdgcn_s_barrier();

        const unsigned short* pa = lsa[cb];
        const unsigned short* pb = lsb[cb];
        bf16x8 af[4], bfr[4];
#pragma unroll
        for (int i = 0; i < 4; ++i)
            af[i] = *(const bf16x8*)&pa[(wm + i * 16 + l15) * 32 + rch];
#pragma unroll
        for (int j = 0; j < 4; ++j)
            bfr[j] = *(const bf16x8*)&pb[(wn + j * 16 + l15) * 32 + rch];
#pragma unroll
        for (int i = 0; i < 4; ++i)
#pragma unroll
            for (int j = 0; j < 4; ++j)
                acc[i][j] = MFMA16(af[i], bfr[j], acc[i][j], 0, 0, 0);

        asm volatile("s_waitcnt lgkmcnt(0)" ::: "memory");
        __builtin_amdgcn_sched_barrier(0);
        __builtin_amdgcn_s_barrier();
    }

    const int which = n0 >> 10;
    if (which == 2) {
#pragma unroll
        for (int j = 0; j < 4; ++j) {
            const int n = n0 + wn + j * 16 + l15;
            const int c = n & 1023;
            const int h = c >> 6, d = c & 63;
            const float bv = bias[n];
#pragma unroll
            for (int i = 0; i < 4; ++i) {
                const int m = m0 + wm + i * 16 + quad * 4;   // r=0 row
                const int b = m >> 10, s = m & 1023;
                us4v pk;
#pragma unroll
                for (int r = 0; r < 4; ++r) pk[r] = f2bf(acc[i][j][r] + bv);
                *(us4v*)&vbT[(size_t)((b * 16 + h) * 64 + d) * 1024 + s] = pk;
            }
        }
    } else {
        unsigned short* __restrict__ dst = (which == 0) ? qb : kb;
        // q scale = 0.125 * log2(e): softmax runs in exp2 domain
        const float sc = (which == 0) ? 0.18033688011112442f : 1.0f;
#pragma unroll
        for (int j = 0; j < 4; ++j) {
            const int n = n0 + wn + j * 16 + l15;
            const int c = n & 1023;
            const int h = c >> 6, d = c & 63;
            const float bv = bias[n];
#pragma unroll
            for (int i = 0; i < 4; ++i)
#pragma unroll
                for (int r = 0; r < 4; ++r) {
                    const int m = m0 + wm + i * 16 + quad * 4 + r;
                    const int b = m >> 10, s = m & 1023;
                    const float v = (acc[i][j][r] + bv) * sc;
                    dst[(size_t)((b * 16 + h) * 1024 + s) * 64 + d] = f2bf(v);
                }
        }
    }
}

// ---------------------------------------------------------------------------
// Kernel 2: flash attention, key-split barrier-free waves.
//   Block = 64 q; wave w owns keys [w*256, w*256+256) for ALL 64 q
//   (4 groups of 16). Per-wave private K/V LDS dbuf staged via gl16;
//   NO barriers in the loop (vmcnt(16) counted waits). Mask (pre-scaled
//   by log2e) enters as the MFMA C operand; softmax = exp2f. Split-key
//   partial O/lsum combined via LDS arena overlay + one __syncthreads.
// Arena 80 KB -> 2 blocks/CU. Grid 2048, XCD-swizzled.
// ---------------------------------------------------------------------------
__global__ __launch_bounds__(256, 2)
void attn_kernel(const unsigned short* __restrict__ qb,
                 const unsigned short* __restrict__ kb,
                 const unsigned short* __restrict__ vbT,  // (bh, d, n)
                 const float* __restrict__ mask2,         // mask * log2e
                 unsigned short* __restrict__ ob)   // (B, N, C) bf16
{
    // per-wave arena, shorts: K dbuf [0,4096) = buf*2048 + h*1024 + row*32
    //                         V dbuf [4096,8192) = 4096 + buf*2048 + d*32
    //                         P lsp  [8192,10240) = 8192 + g*512
    // combine overlay (floats): obuf [g][16][68] at 0; lsums [g][16] at 4352
    __shared__ unsigned short arena[4][10240];   // 80 KB
    const int tid  = threadIdx.x;
    const int wave = tid >> 6, lane = tid & 63;
    const int quad = lane >> 4, l15 = lane & 15;
    const int rch = (quad ^ ((l15 >> 1) & 3)) * 8;   // swizzled read chunk
    const int swp = (l15 & 3) << 1;                  // P chunk-pair swizzle
    const int p  = blockIdx.x;
    const int lg = (p & 7) * 256 + (p >> 3);         // XCD swizzle, 2048 wgs
    const int bh = lg >> 4;                          // b*16+h
    const int q0 = (lg & 15) * 64;
    const int b = bh >> 4, h = bh & 15;

    const unsigned short* __restrict__ kbase = kb + (size_t)bh * 65536;
    const unsigned short* __restrict__ vtb  = vbT + (size_t)bh * 65536;
    const int kw0 = wave * 256;                      // wave's key range
    const int scol = ((lane & 3) ^ ((lane >> 3) & 3)) * 8;   // swizzled stage
    const int srow = lane >> 2;                      // 0..15
    unsigned short* aw = arena[wave];

    // Q fragments, 4 groups (B-operand: n=l15=q, k=quad*8+j=d), pre-scaled
    bf16x8 bq[4][2];
#pragma unroll
    for (int g = 0; g < 4; ++g) {
        const unsigned short* qrow =
            qb + (size_t)(bh * 1024 + q0 + g * 16 + l15) * 64;
        bq[g][0] = *(const bf16x8*)(qrow + quad * 8);
        bq[g][1] = *(const bf16x8*)(qrow + 32 + quad * 8);
    }

    float lsum[4] = {0.f, 0.f, 0.f, 0.f};
    f32x4 oacc[4][4];    // [g][ntd]: O[d=ntd*16+quad*4+r][q=l15] partial
#pragma unroll
    for (int g = 0; g < 4; ++g)
#pragma unroll
        for (int nt = 0; nt < 4; ++nt) oacc[g][nt] = (f32x4){0.f, 0.f, 0.f, 0.f};

    const size_t mrow = (size_t)(q0 + l15) * 1024 + kw0;

#define STAGE(bufi, t) do {                                                   \
    const int kb0 = kw0 + (t) * 32;                                           \
    gl16(kbase + (size_t)(kb0 + srow) * 64 + scol,                            \
         aw + (bufi) * 2048 + srow * 32);                                     \
    gl16(kbase + (size_t)(kb0 + 16 + srow) * 64 + scol,                       \
         aw + (bufi) * 2048 + 512 + srow * 32);                               \
    gl16(kbase + (size_t)(kb0 + srow) * 64 + 32 + scol,                       \
         aw + (bufi) * 2048 + 1024 + srow * 32);                              \
    gl16(kbase + (size_t)(kb0 + 16 + srow) * 64 + 32 + scol,                  \
         aw + (bufi) * 2048 + 1536 + srow * 32);                              \
    gl16(vtb + (size_t)(srow) * 1024 + kb0 + scol,                            \
         aw + 4096 + (bufi) * 2048 + srow * 32);                              \
    gl16(vtb + (size_t)(16 + srow) * 1024 + kb0 + scol,                       \
         aw + 4096 + (bufi) * 2048 + 512 + srow * 32);                        \
    gl16(vtb + (size_t)(32 + srow) * 1024 + kb0 + scol,                       \
         aw + 4096 + (bufi) * 2048 + 1024 + srow * 32);                       \
    gl16(vtb + (size_t)(48 + srow) * 1024 + kb0 + scol,                       \
         aw + 4096 + (bufi) * 2048 + 1536 + srow * 32);                       \
} while (0)

#define LOADMASK(mv, t) do {                                                  \
    _Pragma("unroll")                                                         \
    for (int g = 0; g < 4; ++g) {                                             \
        (mv)[g][0] = *(const f32x4*)&mask2[mrow + (size_t)g * 16384 +         \
                                           (t) * 32 + quad * 4];              \
        (mv)[g][1] = *(const f32x4*)&mask2[mrow + (size_t)g * 16384 +         \
                                           (t) * 32 + 16 + quad * 4];         \
    }                                                                         \
} while (0)

    f32x4 mvb[2][4][2];
    STAGE(0, 0);
    LOADMASK(mvb[0], 0);

#pragma unroll 2
    for (int t = 0; t < 8; ++t) {
        const int par = t & 1;
        if (t < 7) {
            STAGE(par ^ 1, t + 1);
            LOADMASK(mvb[par ^ 1], t + 1);
            asm volatile("s_waitcnt vmcnt(16)" ::: "memory"); // tile t landed
        } else {
            asm volatile("s_waitcnt vmcnt(0)" ::: "memory");
        }
        __builtin_amdgcn_sched_barrier(0);

        const unsigned short* kbuf = aw + par * 2048;
        const unsigned short* vbuf = aw + 4096 + par * 2048;
        bf16x8 kf[2][2], vf[4];
#pragma unroll
        for (int nt = 0; nt < 2; ++nt)
#pragma unroll
            for (int hh = 0; hh < 2; ++hh)
                kf[nt][hh] = *(const bf16x8*)
                    &kbuf[hh * 1024 + (nt * 16 + l15) * 32 + rch];
#pragma unroll
        for (int d = 0; d < 4; ++d)
            vf[d] = *(const bf16x8*)&vbuf[(d * 16 + l15) * 32 + rch];

#pragma unroll
        for (int g = 0; g < 4; ++g) {
            // S^T = K Q^T + mask (mask as C-init; exp2 domain)
            __builtin_amdgcn_s_setprio(1);
            f32x4 s0 = MFMA16(kf[0][0], bq[g][0], mvb[par][g][0], 0, 0, 0);
            s0 = MFMA16(kf[0][1], bq[g][1], s0, 0, 0, 0);
            f32x4 s1 = MFMA16(kf[1][0], bq[g][0], mvb[par][g][1], 0, 0, 0);
            s1 = MFMA16(kf[1][1], bq[g][1], s1, 0, 0, 0);
            __builtin_amdgcn_s_setprio(0);

            // p = exp2(s) -> per-group P scratch (pair-swizzled chunks)
            us4v pk0, pk1;
#pragma unroll
            for (int r = 0; r < 4; ++r) {
                const float p0 = exp2f(s0[r]);
                const float p1 = exp2f(s1[r]);
                lsum[g] += p0 + p1;
                pk0[r] = f2bf(p0);
                pk1[r] = f2bf(p1);
            }
            unsigned short* lp = aw + 8192 + g * 512;
            *(us4v*)&lp[l15 * 32 + ((quad ^ swp)) * 4] = pk0;
            *(us4v*)&lp[l15 * 32 + (((4 + quad) ^ swp)) * 4] = pk1;
            const bf16x8 pbv =
                *(const bf16x8*)&lp[l15 * 32 + ((2 * quad) ^ swp) * 4];

            // O += (V^T as A) x (P^T as B), K=32 in one MFMA per d-tile
            __builtin_amdgcn_s_setprio(1);
#pragma unroll
            for (int d = 0; d < 4; ++d)
                oacc[g][d] = MFMA16(vf[d], pbv, oacc[g][d], 0, 0, 0);
            __builtin_amdgcn_s_setprio(0);
        }
    }
#undef STAGE
#undef LOADMASK

    // reduce lsum across quads (lane bits 4,5)
#pragma unroll
    for (int g = 0; g < 4; ++g) {
        lsum[g] += __shfl_xor(lsum[g], 16, 64);
        lsum[g] += __shfl_xor(lsum[g], 32, 64);
    }

    // write partial O + lsum into this wave's arena (overlay; own loop done)
    float* obw = (float*)aw;
#pragma unroll
    for (int g = 0; g < 4; ++g)
#pragma unroll
        for (int d = 0; d < 4; ++d)
            *(f32x4*)&obw[g * 1088 + l15 * 68 + d * 16 + quad * 4] = oacc[g][d];
    if (quad == 0) {
#pragma unroll
        for (int g = 0; g < 4; ++g) obw[4352 + g * 16 + l15] = lsum[g];
    }
    __syncthreads();

    // combine: wave w produces q-group g=w; sum 4 key-partials
    f32x4 fo[4];
#pragma unroll
    for (int k = 0; k < 4; ++k) fo[k] = (f32x4){0.f, 0.f, 0.f, 0.f};
    float ls = 0.f;
#pragma unroll
    for (int w2 = 0; w2 < 4; ++w2) {
        const float* src = (const float*)arena[w2];
#pragma unroll
        for (int k = 0; k < 4; ++k) {
            const f32x4 v =
                *(const f32x4*)&src[wave * 1088 + l15 * 68 + quad * 16 + k * 4];
            fo[k] += v;
        }
        ls += src[4352 + wave * 16 + l15];
    }
    const float inv = 1.0f / ls;
    unsigned short* orow =
        ob + (size_t)(b * 1024 + q0 + wave * 16 + l15) * 1024 + h * 64
           + quad * 16;
#pragma unroll
    for (int k = 0; k < 4; ++k) {
        us4v o;
#pragma unroll
        for (int r = 0; r < 4; ++r) o[r] = f2bf(fo[k][r] * inv);
        *(us4v*)&orow[k * 4] = o;
    }
}

// ---------------------------------------------------------------------------
// Kernel 3: out = ob(bf16) @ woutb^T + out_b, fp32 to d_out (R13 unchanged).
// ---------------------------------------------------------------------------
__global__ __launch_bounds__(256, 3)
void out_gemm(const unsigned short* __restrict__ a,   // (8192,1024) bf16
              const unsigned short* __restrict__ wb,  // (1024,1024) bf16
              const float* __restrict__ bias, float* __restrict__ out)
{
    __shared__ unsigned short lsa[3][128 * 32];
    __shared__ unsigned short lsb[3][128 * 32];
    const int tid  = threadIdx.x;
    const int wave = tid >> 6, lane = tid & 63;
    const int quad = lane >> 4, l15 = lane & 15;
    const int rch = (quad ^ ((l15 >> 1) & 3)) * 8;
    const int m0 = blockIdx.x * 128, n0 = blockIdx.y * 128;
    const int wm = (wave & 1) * 64, wn = (wave >> 1) * 64;

    const int srow = wave * 32 + (lane >> 2);
    const int scol = ((lane & 3) ^ ((lane >> 3) & 3)) * 8;
    const unsigned short* ga = a + (size_t)(m0 + srow) * 1024 + scol;
    const unsigned short* gb = wb + (size_t)(n0 + srow) * 1024 + scol;
    const int so0 = (wave * 32) * 32;
    const int so1 = (wave * 32 + 16) * 32;

    f32x4 acc[4][4];
#pragma unroll
    for (int i = 0; i < 4; ++i)
#pragma unroll
        for (int j = 0; j < 4; ++j) acc[i][j] = (f32x4){0.f, 0.f, 0.f, 0.f};

    gl16(ga, &lsa[0][so0]);
    gl16(ga + 16 * 1024, &lsa[0][so1]);
    gl16(gb, &lsb[0][so0]);
    gl16(gb + 16 * 1024, &lsb[0][so1]);
    gl16(ga + 32, &lsa[1][so0]);
    gl16(ga + 16 * 1024 + 32, &lsa[1][so1]);
    gl16(gb + 32, &lsb[1][so0]);
    gl16(gb + 16 * 1024 + 32, &lsb[1][so1]);

    for (int kt = 0; kt < 32; ++kt) {
        const int cb = kt % 3;
        if (kt < 30) {
            const int k0 = (kt + 2) * 32;
            const int sb = (kt + 2) % 3;
            gl16(ga + k0, &lsa[sb][so0]);
            gl16(ga + 16 * 1024 + k0, &lsa[sb][so1]);
            gl16(gb + k0, &lsb[sb][so0]);
            gl16(gb + 16 * 1024 + k0, &lsb[sb][so1]);
            asm volatile("s_waitcnt vmcnt(8)" ::: "memory");
        } else if (kt == 30) {
            asm volatile("s_waitcnt vmcnt(4)" ::: "memory");
        } else {
            asm volatile("s_waitcnt vmcnt(0)" ::: "memory");
        }
        __builtin_amdgcn_s_barrier();

        const unsigned short* pa = lsa[cb];
        const unsigned short* pb = lsb[cb];
        bf16x8 af[4], bfr[4];
#pragma unroll
        for (int i = 0; i < 4; ++i)
            af[i] = *(const bf16x8*)&pa[(wm + i * 16 + l15) * 32 + rch];
#pragma unroll
        for (int j = 0; j < 4; ++j)
            bfr[j] = *(const bf16x8*)&pb[(wn + j * 16 + l15) * 32 + rch];
#pragma unroll
        for (int i = 0; i < 4; ++i)
#pragma unroll
            for (int j = 0; j < 4; ++j)
                acc[i][j] = MFMA16(af[i], bfr[j], acc[i][j], 0, 0, 0);

        asm volatile("s_waitcnt lgkmcnt(0)" ::: "memory");
        __builtin_amdgcn_sched_barrier(0);
        __builtin_amdgcn_s_barrier();
    }

#pragma unroll
    for (int j = 0; j < 4; ++j) {
        const int n = n0 + wn + j * 16 + l15;
        const float bv = bias[n];
#pragma unroll
        for (int i = 0; i < 4; ++i)
#pragma unroll
            for (int r = 0; r < 4; ++r) {
                const int m = m0 + wm + i * 16 + quad * 4 + r;
                out[(size_t)m * 1024 + n] = acc[i][j][r] + bv;
            }
    }
}

// ---------------------------------------------------------------------------
extern "C" void kernel_launch(void* const* d_in, const int* in_sizes, int n_in,
                              void* d_out, int out_size, void* d_ws, size_t ws_size,
                              hipStream_t stream) {
    const float* x    = (const float*)d_in[0];   // (8, 1024, 1024)
    const float* mask = (const float*)d_in[1];   // (1024, 1024)
    const float* win  = (const float*)d_in[2];   // (3072, 1024)
    const float* bin  = (const float*)d_in[3];   // (3072)
    const float* wout = (const float*)d_in[4];   // (1024, 1024)
    const float* bout = (const float*)d_in[5];   // (1024)
    float* out = (float*)d_out;                  // (8, 1024, 1024)

    char* ws = (char*)d_ws;
    unsigned short* xb = (unsigned short*)(ws);
    unsigned short* ob = (unsigned short*)(ws);                       // overlays xb
    unsigned short* qb = (unsigned short*)(ws + (size_t)(16 << 20));
    unsigned short* kb = (unsigned short*)(ws + (size_t)(32 << 20));
    unsigned short* vbT = (unsigned short*)(ws + (size_t)(48 << 20));
    unsigned short* winb  = (unsigned short*)d_out;                   // [0, 6M)
    float* mask2 = (float*)((char*)d_out + (size_t)(6 << 20));        // [6M,10M)
    unsigned short* woutb = qb;   // overlays qb AFTER attn (qb dead) — no race

    cvt_bf16<<<dim3(8192), 256, 0, stream>>>(x, xb, 8 * 1024 * 1024 / 4);
    cvt_bf16<<<dim3(3072), 256, 0, stream>>>(win, winb, 3 * 1024 * 1024 / 4);
    scale_f32<<<dim3(1024), 256, 0, stream>>>(mask, mask2, 1024 * 1024 / 4);
    qkv_gemm<<<dim3(64, 24), 256, 0, stream>>>(xb, winb, bin, qb, kb, vbT);
    attn_kernel<<<dim3(2048), 256, 0, stream>>>(qb, kb, vbT, mask2, ob);
    cvt_bf16<<<dim3(1024), 256, 0, stream>>>(wout, woutb, 1024 * 1024 / 4);
    out_gemm<<<dim3(64, 8), 256, 0, stream>>>(ob, woutb, bout, out);
}

// Round 11
// 280.225 us; speedup vs baseline: 1.2981x; 1.0482x over previous
//
#include <hip/hip_runtime.h>

// ---------------------------------------------------------------------------
// Fused MHA forward on MI355X (gfx950), bf16 MFMA path, round 16.
// B=8, N=1024, C=1024, H=16, D=64.  M = B*N = 8192.
// ws (64 MB): [0,16M) xb then ob; [16,32M) qb then woutb; [32,48M) kb;
//             [48,64M) vbT.
// d_out: [0,6M) winb; [6M,10M) mask*log2e — dead before out_gemm writes.
// NEW vs round 15 (attn rebuilt on 32x32 MFMA + in-register P; GEMMs=R13):
//  * attn: swapped QK^T at 32x32 (S^T=MFMA32(K,Q), C row=(reg&3)+8(reg>>2)
//    +4(l>>5), col=q=l&31). Mask (x log2e) enters as MFMA C operand ->
//    zero mask-add VALU; softmax = exp2f. P->PV B-frag built FULLY IN
//    REGISTERS: 16 v_cvt_pk_bf16_f32 + 8 v_permlane32_swap_b32 per iter
//    (T12) — P LDS round-trip deleted (no lsp, 12 DS-ops/iter removed).
//    K/V gl16 dbuf + 2-phase __syncthreads = the proven R5 95us loop;
//    staging swizzle upgraded to S(r)=((r>>1)^(r>>3))&3 (bank floor for
//    32-row fragment reads). LDS 32KB, 3 blk/CU. Grid 1024, XCD swizzle.
// ---------------------------------------------------------------------------

typedef __bf16 bf16x8 __attribute__((ext_vector_type(8)));
typedef float f32x4 __attribute__((ext_vector_type(4)));
typedef float f32x16 __attribute__((ext_vector_type(16)));
typedef unsigned short us4v __attribute__((ext_vector_type(4)));
typedef unsigned int u32x4 __attribute__((ext_vector_type(4)));

#define MFMA16 __builtin_amdgcn_mfma_f32_16x16x32_bf16
#define MFMA32 __builtin_amdgcn_mfma_f32_32x32x16_bf16

__device__ __forceinline__ unsigned short f2bf(float f) {
    return __builtin_bit_cast(unsigned short, (__bf16)f);   // native cvt, RNE
}

__device__ __forceinline__ us4v cvt4(float4 v) {
    us4v r;
    r.x = f2bf(v.x); r.y = f2bf(v.y); r.z = f2bf(v.z); r.w = f2bf(v.w);
    return r;
}

__device__ __forceinline__ unsigned cvtpk(float lo, float hi) {
    unsigned r;
    asm volatile("v_cvt_pk_bf16_f32 %0, %1, %2" : "=v"(r) : "v"(lo), "v"(hi));
    return r;
}

// async global->LDS, 16 B per lane; LDS dest = wave-uniform base + lane*16
__device__ __forceinline__ void gl16(const unsigned short* g, unsigned short* l) {
    __builtin_amdgcn_global_load_lds(
        (const __attribute__((address_space(1))) unsigned*)g,
        (__attribute__((address_space(3))) unsigned*)l, 16, 0, 0);
}

// ---------------------------------------------------------------------------
// Kernel 0: fp32 -> bf16 convert (one float4 per thread)
// ---------------------------------------------------------------------------
__global__ __launch_bounds__(256)
void cvt_bf16(const float* __restrict__ src, unsigned short* __restrict__ dst,
              int n4) {
    const int i = blockIdx.x * 256 + threadIdx.x;
    if (i < n4) {
        float4 v = ((const float4*)src)[i];
        ((us4v*)dst)[i] = cvt4(v);
    }
}

// Kernel 0b: scale f32 by log2(e) (for exp2-domain softmax)
__global__ __launch_bounds__(256)
void scale_f32(const float* __restrict__ src, float* __restrict__ dst, int n4) {
    const int i = blockIdx.x * 256 + threadIdx.x;
    if (i < n4) {
        float4 v = ((const float4*)src)[i];
        const float s = 1.4426950408889634f;
        v.x *= s; v.y *= s; v.z *= s; v.w *= s;
        ((float4*)dst)[i] = v;
    }
}

// ---------------------------------------------------------------------------
// Kernel 1: qkv = xb @ winb^T + b_in -> q (x0.125*log2e), k in (B,H,N,D),
//           V written directly transposed as vbT (B,H,D,N) bf16.
// Triple-buffered counted-vmcnt pipeline (R13, unchanged).
// ---------------------------------------------------------------------------
__global__ __launch_bounds__(256, 3)
void qkv_gemm(const unsigned short* __restrict__ xb,   // (8192,1024) bf16
              const unsigned short* __restrict__ wb,   // (3072,1024) bf16
              const float* __restrict__ bias,
              unsigned short* __restrict__ qb, unsigned short* __restrict__ kb,
              unsigned short* __restrict__ vbT)
{
    __shared__ unsigned short lsa[3][128 * 32];
    __shared__ unsigned short lsb[3][128 * 32];
    const int tid  = threadIdx.x;
    const int wave = tid >> 6, lane = tid & 63;
    const int quad = lane >> 4, l15 = lane & 15;
    const int rch = (quad ^ ((l15 >> 1) & 3)) * 8;   // swizzled read chunk
    const int m0 = blockIdx.x * 128, n0 = blockIdx.y * 128;
    const int wm = (wave & 1) * 64, wn = (wave >> 1) * 64;

    const int srow = wave * 32 + (lane >> 2);
    const int scol = ((lane & 3) ^ ((lane >> 3) & 3)) * 8;   // swizzled stage
    const unsigned short* ga = xb + (size_t)(m0 + srow) * 1024 + scol;
    const unsigned short* gb = wb + (size_t)(n0 + srow) * 1024 + scol;
    const int so0 = (wave * 32) * 32;          // stage offsets within a buffer
    const int so1 = (wave * 32 + 16) * 32;

    f32x4 acc[4][4];
#pragma unroll
    for (int i = 0; i < 4; ++i)
#pragma unroll
        for (int j = 0; j < 4; ++j) acc[i][j] = (f32x4){0.f, 0.f, 0.f, 0.f};

    gl16(ga, &lsa[0][so0]);
    gl16(ga + 16 * 1024, &lsa[0][so1]);
    gl16(gb, &lsb[0][so0]);
    gl16(gb + 16 * 1024, &lsb[0][so1]);
    gl16(ga + 32, &lsa[1][so0]);
    gl16(ga + 16 * 1024 + 32, &lsa[1][so1]);
    gl16(gb + 32, &lsb[1][so0]);
    gl16(gb + 16 * 1024 + 32, &lsb[1][so1]);

    for (int kt = 0; kt < 32; ++kt) {
        const int cb = kt % 3;
        if (kt < 30) {                         // stage kt+2 (distance 2)
            const int k0 = (kt + 2) * 32;
            const int sb = (kt + 2) % 3;
            gl16(ga + k0, &lsa[sb][so0]);
            gl16(ga + 16 * 1024 + k0, &lsa[sb][so1]);
            gl16(gb + k0, &lsb[sb][so0]);
            gl16(gb + 16 * 1024 + k0, &lsb[sb][so1]);
            asm volatile("s_waitcnt vmcnt(8)" ::: "memory");
        } else if (kt == 30) {
            asm volatile("s_waitcnt vmcnt(4)" ::: "memory");
        } else {
            asm volatile("s_waitcnt vmcnt(0)" ::: "memory");
        }
        __builtin_amdgcn_s_barrier();

        const unsigned short* pa = lsa[cb];
        const unsigned short* pb = lsb[cb];
        bf16x8 af[4], bfr[4];
#pragma unroll
        for (int i = 0; i < 4; ++i)
            af[i] = *(const bf16x8*)&pa[(wm + i * 16 + l15) * 32 + rch];
#pragma unroll
        for (int j = 0; j < 4; ++j)
            bfr[j] = *(const bf16x8*)&pb[(wn + j * 16 + l15) * 32 + rch];
#pragma unroll
        for (int i = 0; i < 4; ++i)
#pragma unroll
            for (int j = 0; j < 4; ++j)
                acc[i][j] = MFMA16(af[i], bfr[j], acc[i][j], 0, 0, 0);

        asm volatile("s_waitcnt lgkmcnt(0)" ::: "memory");
        __builtin_amdgcn_sched_barrier(0);
        __builtin_amdgcn_s_barrier();
    }

    const int which = n0 >> 10;
    if (which == 2) {
#pragma unroll
        for (int j = 0; j < 4; ++j) {
            const int n = n0 + wn + j * 16 + l15;
            const int c = n & 1023;
            const int h = c >> 6, d = c & 63;
            const float bv = bias[n];
#pragma unroll
            for (int i = 0; i < 4; ++i) {
                const int m = m0 + wm + i * 16 + quad * 4;   // r=0 row
                const int b = m >> 10, s = m & 1023;
                us4v pk;
#pragma unroll
                for (int r = 0; r < 4; ++r) pk[r] = f2bf(acc[i][j][r] + bv);
                *(us4v*)&vbT[(size_t)((b * 16 + h) * 64 + d) * 1024 + s] = pk;
            }
        }
    } else {
        unsigned short* __restrict__ dst = (which == 0) ? qb : kb;
        // q scale = 0.125 * log2(e): softmax runs in exp2 domain
        const float sc = (which == 0) ? 0.18033688011112442f : 1.0f;
#pragma unroll
        for (int j = 0; j < 4; ++j) {
            const int n = n0 + wn + j * 16 + l15;
            const int c = n & 1023;
            const int h = c >> 6, d = c & 63;
            const float bv = bias[n];
#pragma unroll
            for (int i = 0; i < 4; ++i)
#pragma unroll
                for (int r = 0; r < 4; ++r) {
                    const int m = m0 + wm + i * 16 + quad * 4 + r;
                    const int b = m >> 10, s = m & 1023;
                    const float v = (acc[i][j][r] + bv) * sc;
                    dst[(size_t)((b * 16 + h) * 1024 + s) * 64 + d] = f2bf(v);
                }
        }
    }
}

// ---------------------------------------------------------------------------
// Kernel 2: flash attention, 32x32 MFMA, in-register P (T12).
//   QBLK=128: wave w owns q-col = q0+w*32+(l&31); all keys iterated in
//   64-key tiles (2x 32-key sub-tiles). S^T = MFMA32(K, Q, C=mask2^T):
//   lane holds 16 p for its q (keys (r&3)+8(r>>2)+4*hl per octet).
//   PV B-frag: cvt_pk pairs + permlane32_swap -> k=8*hl+j mapping direct.
//   O^T accum 2x f32x16. K/V gl16 dbuf, one __syncthreads per tile (R5).
// LDS 32KB -> 3 blk/CU. Grid 1024, XCD-swizzled.
// ---------------------------------------------------------------------------
__global__ __launch_bounds__(256, 3)
void attn_kernel(const unsigned short* __restrict__ qb,
                 const unsigned short* __restrict__ kb,
                 const unsigned short* __restrict__ vbT,  // (bh, d, n)
                 const float* __restrict__ mask2,         // mask * log2e
                 unsigned short* __restrict__ ob)   // (B, N, C) bf16
{
    __shared__ unsigned short lsk[2][2][64 * 32];  // [buf][d-half][key*32]
    __shared__ unsigned short lsv[2][2][64 * 32];  // [buf][key-half][d*32]
    const int tid  = threadIdx.x;
    const int wave = tid >> 6, lane = tid & 63;
    const int r5 = lane & 31, hl = lane >> 5;
    const int rs = ((r5 >> 1) ^ (r5 >> 3)) & 3;    // read-chunk swizzle
    const int p  = blockIdx.x;
    const int lg = (p & 7) * 128 + (p >> 3);       // XCD swizzle (bijective)
    const int bh = lg >> 3;                        // b*16+h
    const int q0 = (lg & 7) * 128;
    const int b = bh >> 4, head = bh & 15;

    const unsigned short* __restrict__ kbase = kb + (size_t)bh * 65536;
    const unsigned short* __restrict__ vtb  = vbT + (size_t)bh * 65536;

    // stage: row r = wave*16 + lane>>2; S(r)=((r>>1)^(r>>3))&3 via lane bits
    const int scol =
        ((lane & 3) ^ ((lane >> 3) & 3) ^ ((2 * wave + (lane >> 5)) & 3)) * 8;
    const unsigned short* gk = kbase + (size_t)(wave * 16 + (lane >> 2)) * 64
                                     + scol;
    const unsigned short* gv = vtb + (size_t)(wave * 16 + (lane >> 2)) * 1024
                                   + scol;
    const int so = (wave * 16) * 32;             // stage offset within a half

    // Q fragments (B-operand: n=q=l&31, k=d=kk*16+8*hl+j), q pre-scaled
    const int q = q0 + wave * 32 + r5;
    bf16x8 bq[4];
    {
        const unsigned short* qrow = qb + (size_t)(bh * 1024 + q) * 64;
#pragma unroll
        for (int kk = 0; kk < 4; ++kk)
            bq[kk] = *(const bf16x8*)(qrow + kk * 16 + hl * 8);
    }

    float lsum = 0.f;
    f32x16 acc[2];                 // [dt]: O^T[d=32dt+(r&3)+8(r>>2)+4hl][q]
#pragma unroll
    for (int dt = 0; dt < 2; ++dt)
#pragma unroll
        for (int r = 0; r < 16; ++r) acc[dt][r] = 0.f;

    const float* __restrict__ mq = mask2 + (size_t)q * 1024;

    // prologue: stage tile 0 into buf 0
    gl16(gk, &lsk[0][0][so]);
    gl16(gk + 32, &lsk[0][1][so]);
    gl16(gv, &lsv[0][0][so]);
    gl16(gv + 32, &lsv[0][1][so]);
    __syncthreads();

    int buf = 0;
    for (int kt = 0; kt < 16; ++kt) {
        // masks for CURRENT tile (oldest vmem -> QK's wait leaves the
        // younger prefetch gl16s in flight)
        f32x16 msk[2];
#pragma unroll
        for (int t32 = 0; t32 < 2; ++t32)
#pragma unroll
            for (int oct = 0; oct < 4; ++oct) {
                const float4 mv = *(const float4*)
                    &mq[kt * 64 + t32 * 32 + oct * 8 + hl * 4];
                msk[t32][4 * oct + 0] = mv.x;
                msk[t32][4 * oct + 1] = mv.y;
                msk[t32][4 * oct + 2] = mv.z;
                msk[t32][4 * oct + 3] = mv.w;
            }
        __builtin_amdgcn_sched_barrier(0);     // keep mask loads oldest
        if (kt < 15) {                         // stage next tile early
            gl16(gk + (size_t)(kt + 1) * 4096, &lsk[buf ^ 1][0][so]);
            gl16(gk + (size_t)(kt + 1) * 4096 + 32, &lsk[buf ^ 1][1][so]);
            gl16(gv + (size_t)(kt + 1) * 64, &lsv[buf ^ 1][0][so]);
            gl16(gv + (size_t)(kt + 1) * 64 + 32, &lsv[buf ^ 1][1][so]);
        }

#pragma unroll
        for (int t32 = 0; t32 < 2; ++t32) {
            // S^T = K Q^T + mask (C operand), 32 keys x 32 q, 4x K=16
            f32x16 s = msk[t32];
            __builtin_amdgcn_s_setprio(1);
#pragma unroll
            for (int kk = 0; kk < 4; ++kk) {
                const unsigned short* kp = lsk[buf][kk >> 1];
                const int c4 = 2 * (kk & 1) + hl;
                const bf16x8 ka = *(const bf16x8*)
                    &kp[(t32 * 32 + r5) * 32 + ((c4 ^ rs) * 8)];
                s = MFMA32(ka, bq[kk], s, 0, 0, 0);
            }
            __builtin_amdgcn_s_setprio(0);

            // softmax: p = exp2(s); pack + permlane32_swap -> B-frags
            float pv[16];
            float ts = 0.f;
#pragma unroll
            for (int r = 0; r < 16; ++r) {
                pv[r] = exp2f(s[r]);
                ts += pv[r];
            }
            lsum += ts;

            bf16x8 pfr[2];
#pragma unroll
            for (int cl = 0; cl < 2; ++cl) {
                unsigned xa = cvtpk(pv[8 * cl + 0], pv[8 * cl + 1]);
                unsigned xb = cvtpk(pv[8 * cl + 2], pv[8 * cl + 3]);
                unsigned ya = cvtpk(pv[8 * cl + 4], pv[8 * cl + 5]);
                unsigned yb = cvtpk(pv[8 * cl + 6], pv[8 * cl + 7]);
                asm volatile("v_permlane32_swap_b32 %0, %1"
                             : "+v"(xa), "+v"(ya));
                asm volatile("v_permlane32_swap_b32 %0, %1"
                             : "+v"(xb), "+v"(yb));
                const u32x4 t = {xa, xb, ya, yb};
                pfr[cl] = __builtin_bit_cast(bf16x8, t);
            }

            // O^T += V^T x P^T  (A = V^T frag, B = P frag), K=16 per chunk
            __builtin_amdgcn_s_setprio(1);
#pragma unroll
            for (int cl = 0; cl < 2; ++cl) {
                const int cg = t32 * 2 + cl;
                const unsigned short* vp = lsv[buf][cg >> 1];
                const int c4v = 2 * (cg & 1) + hl;
                const int voff = (c4v ^ rs) * 8;
#pragma unroll
                for (int dt = 0; dt < 2; ++dt) {
                    const bf16x8 va = *(const bf16x8*)
                        &vp[(dt * 32 + r5) * 32 + voff];
                    acc[dt] = MFMA32(va, pfr[cl], acc[dt], 0, 0, 0);
                }
            }
            __builtin_amdgcn_s_setprio(0);
        }

        __syncthreads();                       // drain stage + protect bufs
        buf ^= 1;
    }

    // lane covers keys with (key&7)>>2 == hl; partner lane has the rest
    lsum += __shfl_xor(lsum, 32, 64);
    const float inv = 1.0f / lsum;

    unsigned short* orow =
        ob + (size_t)(b * 1024 + q) * 1024 + head * 64;
#pragma unroll
    for (int dt = 0; dt < 2; ++dt)
#pragma unroll
        for (int oct = 0; oct < 4; ++oct) {
            us4v o;
#pragma unroll
            for (int r = 0; r < 4; ++r)
                o[r] = f2bf(acc[dt][4 * oct + r] * inv);
            *(us4v*)&orow[dt * 32 + oct * 8 + hl * 4] = o;
        }
}

// ---------------------------------------------------------------------------
// Kernel 3: out = ob(bf16) @ woutb^T + out_b, fp32 to d_out (R13 unchanged).
// ---------------------------------------------------------------------------
__global__ __launch_bounds__(256, 3)
void out_gemm(const unsigned short* __restrict__ a,   // (8192,1024) bf16
              const unsigned short* __restrict__ wb,  // (1024,1024) bf16
              const float* __restrict__ bias, float* __restrict__ out)
{
    __shared__ unsigned short lsa[3][128 * 32];
    __shared__ unsigned short lsb[3][128 * 32];
    const int tid  = threadIdx.x;
    const int wave = tid >> 6, lane = tid & 63;
    const int quad = lane >> 4, l15 = lane & 15;
    const int rch = (quad ^ ((l15 >> 1) & 3)) * 8;
    const int m0 = blockIdx.x * 128, n0 = blockIdx.y * 128;
    const int wm = (wave & 1) * 64, wn = (wave >> 1) * 64;

    const int srow = wave * 32 + (lane >> 2);
    const int scol = ((lane & 3) ^ ((lane >> 3) & 3)) * 8;
    const unsigned short* ga = a + (size_t)(m0 + srow) * 1024 + scol;
    const unsigned short* gb = wb + (size_t)(n0 + srow) * 1024 + scol;
    const int so0 = (wave * 32) * 32;
    const int so1 = (wave * 32 + 16) * 32;

    f32x4 acc[4][4];
#pragma unroll
    for (int i = 0; i < 4; ++i)
#pragma unroll
        for (int j = 0; j < 4; ++j) acc[i][j] = (f32x4){0.f, 0.f, 0.f, 0.f};

    gl16(ga, &lsa[0][so0]);
    gl16(ga + 16 * 1024, &lsa[0][so1]);
    gl16(gb, &lsb[0][so0]);
    gl16(gb + 16 * 1024, &lsb[0][so1]);
    gl16(ga + 32, &lsa[1][so0]);
    gl16(ga + 16 * 1024 + 32, &lsa[1][so1]);
    gl16(gb + 32, &lsb[1][so0]);
    gl16(gb + 16 * 1024 + 32, &lsb[1][so1]);

    for (int kt = 0; kt < 32; ++kt) {
        const int cb = kt % 3;
        if (kt < 30) {
            const int k0 = (kt + 2) * 32;
            const int sb = (kt + 2) % 3;
            gl16(ga + k0, &lsa[sb][so0]);
            gl16(ga + 16 * 1024 + k0, &lsa[sb][so1]);
            gl16(gb + k0, &lsb[sb][so0]);
            gl16(gb + 16 * 1024 + k0, &lsb[sb][so1]);
            asm volatile("s_waitcnt vmcnt(8)" ::: "memory");
        } else if (kt == 30) {
            asm volatile("s_waitcnt vmcnt(4)" ::: "memory");
        } else {
            asm volatile("s_waitcnt vmcnt(0)" ::: "memory");
        }
        __builtin_amdgcn_s_barrier();

        const unsigned short* pa = lsa[cb];
        const unsigned short* pb = lsb[cb];
        bf16x8 af[4], bfr[4];
#pragma unroll
        for (int i = 0; i < 4; ++i)
            af[i] = *(const bf16x8*)&pa[(wm + i * 16 + l15) * 32 + rch];
#pragma unroll
        for (int j = 0; j < 4; ++j)
            bfr[j] = *(const bf16x8*)&pb[(wn + j * 16 + l15) * 32 + rch];
#pragma unroll
        for (int i = 0; i < 4; ++i)
#pragma unroll
            for (int j = 0; j < 4; ++j)
                acc[i][j] = MFMA16(af[i], bfr[j], acc[i][j], 0, 0, 0);

        asm volatile("s_waitcnt lgkmcnt(0)" ::: "memory");
        __builtin_amdgcn_sched_barrier(0);
        __builtin_amdgcn_s_barrier();
    }

#pragma unroll
    for (int j = 0; j < 4; ++j) {
        const int n = n0 + wn + j * 16 + l15;
        const float bv = bias[n];
#pragma unroll
        for (int i = 0; i < 4; ++i)
#pragma unroll
            for (int r = 0; r < 4; ++r) {
                const int m = m0 + wm + i * 16 + quad * 4 + r;
                out[(size_t)m * 1024 + n] = acc[i][j][r] + bv;
            }
    }
}

// ---------------------------------------------------------------------------
extern "C" void kernel_launch(void* const* d_in, const int* in_sizes, int n_in,
                              void* d_out, int out_size, void* d_ws, size_t ws_size,
                              hipStream_t stream) {
    const float* x    = (const float*)d_in[0];   // (8, 1024, 1024)
    const float* mask = (const float*)d_in[1];   // (1024, 1024)
    const float* win  = (const float*)d_in[2];   // (3072, 1024)
    const float* bin  = (const float*)d_in[3];   // (3072)
    const float* wout = (const float*)d_in[4];   // (1024, 1024)
    const float* bout = (const float*)d_in[5];   // (1024)
    float* out = (float*)d_out;                  // (8, 1024, 1024)

    char* ws = (char*)d_ws;
    unsigned short* xb = (unsigned short*)(ws);
    unsigned short* ob = (unsigned short*)(ws);                       // overlays xb
    unsigned short* qb = (unsigned short*)(ws + (size_t)(16 << 20));
    unsigned short* kb = (unsigned short*)(ws + (size_t)(32 << 20));
    unsigned short* vbT = (unsigned short*)(ws + (size_t)(48 << 20));
    unsigned short* winb  = (unsigned short*)d_out;                   // [0, 6M)
    float* mask2 = (float*)((char*)d_out + (size_t)(6 << 20));        // [6M,10M)
    unsigned short* woutb = qb;   // overlays qb AFTER attn (qb dead) — no race

    cvt_bf16<<<dim3(8192), 256, 0, stream>>>(x, xb, 8 * 1024 * 1024 / 4);
    cvt_bf16<<<dim3(3072), 256, 0, stream>>>(win, winb, 3 * 1024 * 1024 / 4);
    scale_f32<<<dim3(1024), 256, 0, stream>>>(mask, mask2, 1024 * 1024 / 4);
    qkv_gemm<<<dim3(64, 24), 256, 0, stream>>>(xb, winb, bin, qb, kb, vbT);
    attn_kernel<<<dim3(1024), 256, 0, stream>>>(qb, kb, vbT, mask2, ob);
    cvt_bf16<<<dim3(1024), 256, 0, stream>>>(wout, woutb, 1024 * 1024 / 4);
    out_gemm<<<dim3(64, 8), 256, 0, stream>>>(ob, woutb, bout, out);
}